// Round 2
// baseline (559.023 us; speedup 1.0000x reference)
//
#include <hip/hip_runtime.h>
#include <math.h>

#define NFFT 1024
#define HOP 256
#define NFREQ 513
#define TFRAMES 1024
#define NT_TILE 16
#define FSTR 514            /* frame stride in float2 elems (512 + 2 pad) */
#define LOUT  262400        /* (1024 + 256*1023) - 512 */
#define TILE_SAMPS 4864     /* 16*256 + 768 */

__device__ __forceinline__ float2 cadd(float2 a, float2 b){ return make_float2(a.x+b.x, a.y+b.y); }
__device__ __forceinline__ float2 csub(float2 a, float2 b){ return make_float2(a.x-b.x, a.y-b.y); }
__device__ __forceinline__ float2 muli(float2 a){ return make_float2(-a.y, a.x); }   // * i
__device__ __forceinline__ float2 cmul(float2 a, float2 b){
    return make_float2(a.x*b.x - a.y*b.y, a.x*b.y + a.y*b.x);
}

// inverse-sign (e^{+2pi i/8}) radix-8 DFT over v[0..7]
__device__ __forceinline__ void radix8_inv(float2* v) {
    const float C = 0.70710678118654752f;
    float2 a0 = cadd(v[0], v[4]), a1 = csub(v[0], v[4]);
    float2 a2 = cadd(v[2], v[6]), a3 = csub(v[2], v[6]);
    float2 b0 = cadd(v[1], v[5]), b1 = csub(v[1], v[5]);
    float2 b2 = cadd(v[3], v[7]), b3 = csub(v[3], v[7]);
    float2 E0 = cadd(a0, a2), E2 = csub(a0, a2);
    float2 E1 = cadd(a1, muli(a3)), E3 = csub(a1, muli(a3));
    float2 O0 = cadd(b0, b2), O2 = csub(b0, b2);
    float2 O1 = cadd(b1, muli(b3)), O3 = csub(b1, muli(b3));
    float2 T1 = make_float2(C*(O1.x - O1.y),  C*(O1.x + O1.y));   // O1 * w8
    float2 T2 = muli(O2);                                          // O2 * w8^2
    float2 T3 = make_float2(-C*(O3.x + O3.y), C*(O3.x - O3.y));    // O3 * w8^3
    v[0] = cadd(E0, O0); v[4] = csub(E0, O0);
    v[1] = cadd(E1, T1); v[5] = csub(E1, T1);
    v[2] = cadd(E2, T2); v[6] = csub(E2, T2);
    v[3] = cadd(E3, T3); v[7] = csub(E3, T3);
}

// Tw[m] = e^{+2pi i m/512} for m in [0,512) via 256-entry table + sign fold
__device__ __forceinline__ float2 twget(const float2* Tw, int m) {
    float2 t = Tw[m & 255];
    float s = (m & 256) ? -1.f : 1.f;
    return make_float2(s * t.x, s * t.y);
}

// phase-1 storage position of natural index n (0..511), XOR-swizzled
__device__ __forceinline__ int zpos(int n) {
    int blk = n >> 6;
    return blk * 64 + ((n & 63) ^ ((9 * blk) & 63));
}
// storage position of natural FFT OUTPUT index m (octal-digit-reversed + swizzle)
__device__ __forceinline__ int opos(int m) {
    int k0 = m & 7, k1 = (m >> 3) & 7, k2 = m >> 6;
    return k0 * 64 + (((k1 << 3) | k2) ^ ((9 * k0) & 63));
}

__global__ __launch_bounds__(512, 6) void istft_kernel(const float2* __restrict__ x,
                                                       float* __restrict__ out) {
    __shared__ float2 Zc[8 * FSTR];   // 32896 B
    __shared__ float  OA[TILE_SAMPS]; // 19456 B
    __shared__ float2 Tw[256];        //  2048 B   (total 54400 <= 160K/3)

    const int tid  = threadIdx.x;
    const int bc   = blockIdx.y;
    const int tile = blockIdx.x;
    const int t0   = tile * NT_TILE;
    const int S0   = t0 * HOP;

    if (tid < 256) {
        float s, c;
        __sincosf((float)tid * (6.283185307179586f / 512.f), &s, &c);
        Tw[tid] = make_float2(c, s);
    }
    #pragma unroll
    for (int r = 0; r < 10; ++r) { int sl = tid + 512 * r; if (sl < TILE_SAMPS) OA[sl] = 0.f; }

    const int f     = tid >> 6;      // wave-private frame (0..7)
    const int lane6 = tid & 63;
    const int fbase = f * FSTR;

    for (int half = 0; half < 2; ++half) {
        // ---------- phase 1: global load + pack half-size spectrum (natural order) ----------
        {
            const int kg = tid >> 3, tt = tid & 7;
            const int tg = t0 + half * 8 + tt;
            const long baseIn = (long)bc * ((long)NFREQ * TFRAMES);
            const int wbase = tt * FSTR;
            #pragma unroll
            for (int i = 0; i < 5; ++i) {
                int kp = kg + 64 * i;
                if (kp <= 256) {
                    float2 A = x[baseIn + (long)kp * TFRAMES + tg];
                    float2 B = x[baseIn + (long)(512 - kp) * TFRAMES + tg];
                    if (kp == 0) { A.y = 0.f; B.y = 0.f; }  // c2r drops DC/Nyquist imag
                    float si, co;
                    __sincosf((float)kp * (6.283185307179586f / 1024.f), &si, &co);
                    float d2r = A.x - B.x, d2i = A.y + B.y;
                    float o2r = co * d2r - si * d2i, o2i = co * d2i + si * d2r;
                    float s2r = A.x + B.x, s2i = A.y - B.y;
                    Zc[wbase + zpos(kp)] = make_float2(0.5f * (s2r - o2i), 0.5f * (s2i + o2r));
                    if (kp >= 1 && kp <= 255)
                        Zc[wbase + zpos(512 - kp)] = make_float2(0.5f * (s2r + o2i), 0.5f * (o2r - s2i));
                }
            }
        }
        __syncthreads();

        // ---------- radix-8 DIF, stage 1 (stride 64) — wave-private, no syncs below ----------
        {
            const int j = lane6;
            float2 v[8];
            #pragma unroll
            for (int q = 0; q < 8; ++q) v[q] = Zc[fbase + 64 * q + (j ^ ((9 * q) & 63))];
            radix8_inv(v);
            #pragma unroll
            for (int k = 0; k < 8; ++k) {
                float2 w = v[k];
                if (k) w = cmul(w, twget(Tw, j * k));          // W512^{j k}
                Zc[fbase + 64 * k + (j ^ ((9 * k) & 63))] = w;
            }
        }
        // ---------- stage 2 (stride 8 within 64-blocks) ----------
        {
            const int b = lane6 >> 3, jp = lane6 & 7;
            const int sw = (9 * b) & 63, bb = fbase + 64 * b;
            float2 v[8];
            #pragma unroll
            for (int q = 0; q < 8; ++q) v[q] = Zc[bb + ((jp + 8 * q) ^ sw)];
            radix8_inv(v);
            #pragma unroll
            for (int k = 0; k < 8; ++k) {
                float2 w = v[k];
                if (k) w = cmul(w, twget(Tw, 8 * jp * k));     // W64^{jp k}
                Zc[bb + ((jp + 8 * k) ^ sw)] = w;
            }
        }
        // ---------- stage 3 (stride 1 groups of 8) ----------
        {
            const int b = lane6 >> 3, g = lane6 & 7;
            const int sw = (9 * b) & 63, bb = fbase + 64 * b;
            float2 v[8];
            #pragma unroll
            for (int q = 0; q < 8; ++q) v[q] = Zc[bb + ((8 * g + q) ^ sw)];
            radix8_inv(v);
            #pragma unroll
            for (int k = 0; k < 8; ++k) Zc[bb + ((8 * g + k) ^ sw)] = v[k];
        }
        __syncthreads();

        // ---------- window + overlap-add into LDS accumulator ----------
        {
            const int h8 = half * 8;
            #pragma unroll
            for (int r = 0; r < 10; ++r) {
                int sl = tid + 512 * r;
                if (sl >= TILE_SAMPS) break;
                int slh = sl >> 8;
                int tlo = max(slh - 3, h8), thi = min(slh, h8 + 7);
                if (tlo <= thi) {
                    float acc = 0.f;
                    for (int tl = tlo; tl <= thi; ++tl) {
                        int n = sl - (tl << 8);        // 0..1023
                        int m = n >> 1;
                        float2 zz = Zc[(tl - h8) * FSTR + opos(m)];
                        float vv = (n & 1) ? zz.y : zz.x;
                        float2 t = Tw[m & 255];
                        float sg = (m & 256) ? -1.f : 1.f;
                        // cos(2 pi n / 1024): even n -> table; odd n -> half-step rotation
                        float c = (n & 1) ? sg * (t.x * 0.99998117528f - t.y * 0.00613588465f)
                                          : sg * t.x;
                        acc += vv * (1.f - c);
                    }
                    OA[sl] += acc * 0.015625f;   // * sqrt(1024)*0.5/512/2 folded
                }
            }
        }
        __syncthreads();   // protect Zc before next half's phase 1
    }

    // ---------- writeout: interior plain store, boundaries atomic ----------
    #pragma unroll
    for (int r = 0; r < 10; ++r) {
        int sl = tid + 512 * r;
        if (sl >= TILE_SAMPS) break;
        int s = S0 + sl;
        if (s < 512) continue;     // trimmed head
        float v = OA[sl];
        int o = bc * LOUT + (s - 512);
        if (sl >= 768 && sl < 4096) out[o] = v;
        else atomicAdd(&out[o], v);
    }
}

extern "C" void kernel_launch(void* const* d_in, const int* in_sizes, int n_in,
                              void* d_out, int out_size, void* d_ws, size_t ws_size,
                              hipStream_t stream) {
    const float2* x = (const float2*)d_in[0];
    float* out = (float*)d_out;
    (void)in_sizes; (void)n_in; (void)d_ws; (void)ws_size;

    hipMemsetAsync(d_out, 0, (size_t)out_size * sizeof(float), stream);

    dim3 grid(TFRAMES / NT_TILE, 64);   // 64 tiles x 64 (B*C) rows
    dim3 block(512);
    istft_kernel<<<grid, block, 0, stream>>>(x, out);
}

// Round 3
// 453.400 us; speedup vs baseline: 1.2330x; 1.2330x over previous
//
#include <hip/hip_runtime.h>
#include <math.h>

#define NFFT 1024
#define HOP 256
#define NFREQ 513
#define TFRAMES 1024
#define NT_TILE 16
#define FSTR 514            /* frame stride in float2 elems (512 + 2 pad) */
#define LOUT  262400        /* (1024 + 256*1023) - 512 */
#define TILE_SAMPS 4864     /* 16*256 + 768 */

__device__ __forceinline__ float2 cadd(float2 a, float2 b){ return make_float2(a.x+b.x, a.y+b.y); }
__device__ __forceinline__ float2 csub(float2 a, float2 b){ return make_float2(a.x-b.x, a.y-b.y); }
__device__ __forceinline__ float2 muli(float2 a){ return make_float2(-a.y, a.x); }   // * i
__device__ __forceinline__ float2 cmul(float2 a, float2 b){
    return make_float2(a.x*b.x - a.y*b.y, a.x*b.y + a.y*b.x);
}

// inverse-sign (e^{+2pi i/8}) radix-8 DFT on 8 named registers — no arrays, no spill
__device__ __forceinline__ void radix8_inv(float2& v0, float2& v1, float2& v2, float2& v3,
                                           float2& v4, float2& v5, float2& v6, float2& v7) {
    const float C = 0.70710678118654752f;
    float2 a0 = cadd(v0, v4), a1 = csub(v0, v4);
    float2 a2 = cadd(v2, v6), a3 = csub(v2, v6);
    float2 b0 = cadd(v1, v5), b1 = csub(v1, v5);
    float2 b2 = cadd(v3, v7), b3 = csub(v3, v7);
    float2 E0 = cadd(a0, a2), E2 = csub(a0, a2);
    float2 E1 = cadd(a1, muli(a3)), E3 = csub(a1, muli(a3));
    float2 O0 = cadd(b0, b2), O2 = csub(b0, b2);
    float2 O1 = cadd(b1, muli(b3)), O3 = csub(b1, muli(b3));
    float2 T1 = make_float2(C*(O1.x - O1.y),  C*(O1.x + O1.y));   // O1 * w8
    float2 T2 = muli(O2);                                          // O2 * w8^2
    float2 T3 = make_float2(-C*(O3.x + O3.y), C*(O3.x - O3.y));    // O3 * w8^3
    v0 = cadd(E0, O0); v4 = csub(E0, O0);
    v1 = cadd(E1, T1); v5 = csub(E1, T1);
    v2 = cadd(E2, T2); v6 = csub(E2, T2);
    v3 = cadd(E3, T3); v7 = csub(E3, T3);
}

// Tw[m] = e^{+2pi i m/512}, m in [0,512) via 256-entry table + sign fold
__device__ __forceinline__ float2 twget(const float2* Tw, int m) {
    float2 t = Tw[m & 255];
    float s = (m & 256) ? -1.f : 1.f;
    return make_float2(s * t.x, s * t.y);
}

// phase-1 storage position of natural index n (0..511), XOR-swizzled within 64-blocks
__device__ __forceinline__ int zpos(int n) {
    int blk = n >> 6;
    return blk * 64 + ((n & 63) ^ ((9 * blk) & 63));
}
// storage position of natural FFT OUTPUT index m (octal-digit-reversed + swizzle)
__device__ __forceinline__ int opos(int m) {
    int k0 = m & 7, k1 = (m >> 3) & 7, k2 = m >> 6;
    return k0 * 64 + (((k1 << 3) | k2) ^ ((9 * k0) & 63));
}

__global__ __launch_bounds__(512, 4) void istft_kernel(const float2* __restrict__ x,
                                                       float* __restrict__ out) {
    __shared__ float2 Zc[8 * FSTR];   // 32896 B
    __shared__ float  OA[TILE_SAMPS]; // 19456 B
    __shared__ float2 Tw[256];        //  2048 B

    const int tid  = threadIdx.x;
    const int bc   = blockIdx.y;
    const int tile = blockIdx.x;
    const int t0   = tile * NT_TILE;
    const int S0   = t0 * HOP;

    if (tid < 256) {
        float s, c;
        __sincosf((float)tid * (6.283185307179586f / 512.f), &s, &c);
        Tw[tid] = make_float2(c, s);
    }
    #pragma unroll
    for (int r = 0; r < 10; ++r) { int sl = tid + 512 * r; if (sl < TILE_SAMPS) OA[sl] = 0.f; }
    __syncthreads();   // Tw ready before phase 1 reads it

    const int f     = tid >> 6;      // wave-private frame (0..7)
    const int lane6 = tid & 63;
    const int fbase = f * FSTR;

    // half-step rotation e^{+i pi/512} for odd phase-1 bins (and the window)
    const float HR = 0.99998117528260111f, HI = 0.00613588464915448f;

    for (int half = 0; half < 2; ++half) {
        // ---------- phase 1: global load + pack half-size spectrum ----------
        {
            const int kg = tid >> 3, tt = tid & 7;
            const int tg = t0 + half * 8 + tt;
            const long baseIn = (long)bc * ((long)NFREQ * TFRAMES);
            const int wbase = tt * FSTR;
            #pragma unroll
            for (int i = 0; i < 5; ++i) {
                int kp = kg + 64 * i;
                if (kp <= 256) {
                    float2 A = x[baseIn + (long)kp * TFRAMES + tg];
                    float2 B = x[baseIn + (long)(512 - kp) * TFRAMES + tg];
                    if (kp == 0) { A.y = 0.f; B.y = 0.f; }  // c2r drops DC/Nyquist imag
                    // e^{+2pi i kp/1024} from table: Tw[kp>>1], odd kp rotated half-step
                    float2 tw = Tw[kp >> 1];
                    if (kp & 1) tw = make_float2(tw.x * HR - tw.y * HI, tw.x * HI + tw.y * HR);
                    float d2r = A.x - B.x, d2i = A.y + B.y;
                    float o2r = tw.x * d2r - tw.y * d2i, o2i = tw.x * d2i + tw.y * d2r;
                    float s2r = A.x + B.x, s2i = A.y - B.y;
                    Zc[wbase + zpos(kp)] = make_float2(0.5f * (s2r - o2i), 0.5f * (s2i + o2r));
                    if (kp >= 1 && kp <= 255)
                        Zc[wbase + zpos(512 - kp)] = make_float2(0.5f * (s2r + o2i), 0.5f * (o2r - s2i));
                }
            }
        }
        __syncthreads();

        // ---------- radix-8 DIF stage 1 (stride 64) — wave-private, no barriers ----------
        {
            const int j = lane6, zb = fbase;
            float2 v0 = Zc[zb +       (j ^  0)];
            float2 v1 = Zc[zb +  64 + (j ^  9)];
            float2 v2 = Zc[zb + 128 + (j ^ 18)];
            float2 v3 = Zc[zb + 192 + (j ^ 27)];
            float2 v4 = Zc[zb + 256 + (j ^ 36)];
            float2 v5 = Zc[zb + 320 + (j ^ 45)];
            float2 v6 = Zc[zb + 384 + (j ^ 54)];
            float2 v7 = Zc[zb + 448 + (j ^ 63)];
            radix8_inv(v0, v1, v2, v3, v4, v5, v6, v7);
            Zc[zb +       (j ^  0)] = v0;
            Zc[zb +  64 + (j ^  9)] = cmul(v1, twget(Tw, j));
            Zc[zb + 128 + (j ^ 18)] = cmul(v2, twget(Tw, 2 * j));
            Zc[zb + 192 + (j ^ 27)] = cmul(v3, twget(Tw, 3 * j));
            Zc[zb + 256 + (j ^ 36)] = cmul(v4, twget(Tw, 4 * j));
            Zc[zb + 320 + (j ^ 45)] = cmul(v5, twget(Tw, 5 * j));
            Zc[zb + 384 + (j ^ 54)] = cmul(v6, twget(Tw, 6 * j));
            Zc[zb + 448 + (j ^ 63)] = cmul(v7, twget(Tw, 7 * j));
        }
        // ---------- stage 2 (stride 8 within 64-blocks) ----------
        {
            const int b = lane6 >> 3, jp = lane6 & 7;
            const int sw = (9 * b) & 63, bb = fbase + 64 * b;
            float2 v0 = Zc[bb + ((jp     ) ^ sw)];
            float2 v1 = Zc[bb + ((jp +  8) ^ sw)];
            float2 v2 = Zc[bb + ((jp + 16) ^ sw)];
            float2 v3 = Zc[bb + ((jp + 24) ^ sw)];
            float2 v4 = Zc[bb + ((jp + 32) ^ sw)];
            float2 v5 = Zc[bb + ((jp + 40) ^ sw)];
            float2 v6 = Zc[bb + ((jp + 48) ^ sw)];
            float2 v7 = Zc[bb + ((jp + 56) ^ sw)];
            radix8_inv(v0, v1, v2, v3, v4, v5, v6, v7);
            const int m1 = 8 * jp;
            Zc[bb + ((jp     ) ^ sw)] = v0;
            Zc[bb + ((jp +  8) ^ sw)] = cmul(v1, twget(Tw, m1));
            Zc[bb + ((jp + 16) ^ sw)] = cmul(v2, twget(Tw, 2 * m1));
            Zc[bb + ((jp + 24) ^ sw)] = cmul(v3, twget(Tw, 3 * m1));
            Zc[bb + ((jp + 32) ^ sw)] = cmul(v4, twget(Tw, 4 * m1));
            Zc[bb + ((jp + 40) ^ sw)] = cmul(v5, twget(Tw, 5 * m1));
            Zc[bb + ((jp + 48) ^ sw)] = cmul(v6, twget(Tw, 6 * m1));
            Zc[bb + ((jp + 56) ^ sw)] = cmul(v7, twget(Tw, 7 * m1));
        }
        // ---------- stage 3 (contiguous groups of 8, no twiddle) ----------
        {
            const int b = lane6 >> 3, g = lane6 & 7;
            const int sw = (9 * b) & 63, bb = fbase + 64 * b, g8 = 8 * g;
            float2 v0 = Zc[bb + ((g8    ) ^ sw)];
            float2 v1 = Zc[bb + ((g8 + 1) ^ sw)];
            float2 v2 = Zc[bb + ((g8 + 2) ^ sw)];
            float2 v3 = Zc[bb + ((g8 + 3) ^ sw)];
            float2 v4 = Zc[bb + ((g8 + 4) ^ sw)];
            float2 v5 = Zc[bb + ((g8 + 5) ^ sw)];
            float2 v6 = Zc[bb + ((g8 + 6) ^ sw)];
            float2 v7 = Zc[bb + ((g8 + 7) ^ sw)];
            radix8_inv(v0, v1, v2, v3, v4, v5, v6, v7);
            Zc[bb + ((g8    ) ^ sw)] = v0;
            Zc[bb + ((g8 + 1) ^ sw)] = v1;
            Zc[bb + ((g8 + 2) ^ sw)] = v2;
            Zc[bb + ((g8 + 3) ^ sw)] = v3;
            Zc[bb + ((g8 + 4) ^ sw)] = v4;
            Zc[bb + ((g8 + 5) ^ sw)] = v5;
            Zc[bb + ((g8 + 6) ^ sw)] = v6;
            Zc[bb + ((g8 + 7) ^ sw)] = v7;
        }
        __syncthreads();

        // ---------- window + overlap-add into LDS accumulator ----------
        {
            const int h8 = half * 8;
            #pragma unroll
            for (int r = 0; r < 10; ++r) {
                int sl = tid + 512 * r;
                if (sl < TILE_SAMPS) {
                    int slh = sl >> 8;
                    int tlo = max(slh - 3, h8), thi = min(slh, h8 + 7);
                    if (tlo <= thi) {
                        float acc = 0.f;
                        for (int tl = tlo; tl <= thi; ++tl) {
                            int n = sl - (tl << 8);        // 0..1023
                            int m = n >> 1;
                            float2 zz = Zc[(tl - h8) * FSTR + opos(m)];
                            float vv = (n & 1) ? zz.y : zz.x;
                            float2 t = Tw[m & 255];
                            float sg = (m & 256) ? -1.f : 1.f;
                            float c = (n & 1) ? sg * (t.x * HR - t.y * HI) : sg * t.x;
                            acc += vv * (1.f - c);
                        }
                        OA[sl] += acc * 0.015625f;   // sqrt(1024)*0.5/512/2 folded
                    }
                }
            }
        }
        __syncthreads();   // protect Zc before next half's phase 1
    }

    // ---------- writeout: interior plain store, boundaries atomic ----------
    #pragma unroll
    for (int r = 0; r < 10; ++r) {
        int sl = tid + 512 * r;
        if (sl < TILE_SAMPS) {
            int s = S0 + sl;
            if (s >= 512) {   // head trimmed
                float v = OA[sl];
                int o = bc * LOUT + (s - 512);
                if (sl >= 768 && sl < 4096) out[o] = v;
                else atomicAdd(&out[o], v);
            }
        }
    }
}

extern "C" void kernel_launch(void* const* d_in, const int* in_sizes, int n_in,
                              void* d_out, int out_size, void* d_ws, size_t ws_size,
                              hipStream_t stream) {
    const float2* x = (const float2*)d_in[0];
    float* out = (float*)d_out;
    (void)in_sizes; (void)n_in; (void)d_ws; (void)ws_size;

    hipMemsetAsync(d_out, 0, (size_t)out_size * sizeof(float), stream);

    dim3 grid(TFRAMES / NT_TILE, 64);   // 64 tiles x 64 (B*C) rows
    dim3 block(512);
    istft_kernel<<<grid, block, 0, stream>>>(x, out);
}